// Round 1
// 1960.189 us; speedup vs baseline: 1.1250x; 1.1250x over previous
//
#include <hip/hip_runtime.h>

// samx_qkv_1bit R12: latency-overlap restructure of R11.
// R11 was latency-bound: 1 wave/SIMD (grid-bound, 1024 rows = 1024 SIMDs),
// VALUBusy 21%, ~2520 cyc/step of mostly dependent-LDS stalls. Per step, two
// independent dependent chains ran back-to-back: query walk and key-side
// chain machinery. R12 overlaps them:
//   - ALL key-side reads + clone decision hoisted ABOVE the query walk
//     (they depend only on the pre-loaded img). tk[d] prefix-store effect on
//     the clone's transition copy is patched in registers via one ballot.
//   - Stores to FRESH states (flml[j], flml/tr[bb]) issue early (unreachable
//     by the query until the deferred link stores land). Only query-visible
//     stores (tk[cid]=j/bb, flml[d].fl=bb, rla stamps, outr) are deferred.
//   - Run-start mask computed from PRE-redirect img (provably identical:
//     redirect swaps a maximal run of d for an equal run of fresh bb); new
//     chain slot 1 is just flj, so no shuffle depends on the redirect.
//   - selbit (36 VALU) + 2 shfl hops -> mbcnt + one ds_permute push
//     (run-start #q -> slot q+1; non-starts push to trash slot 0, which only
//     lane 0 reads and overrides with j). t2c broadcasts via v_readlane
//     (uniform index, no DS hop) instead of __shfl.
//   - Next step's gathers (tk[cid], flml[cid]) and the query's first
//     iteration loads (tq[w], flml[w]) prefetch at the loop tail, after all
//     stores (same-wave DS ops complete in order), removing the first hop
//     from both chains.
// Cold paths (chain > 64) keep the R10-verified serial fallback verbatim.

#define NSTATES 4096
#define TLEN 2048

typedef unsigned long long u64m;

__global__ __launch_bounds__(64)
void samx_main(const float* __restrict__ q,
               const float* __restrict__ k,
               unsigned* __restrict__ outpos,
               int T, int C) {
  __shared__ unsigned short tr0a[NSTATES];
  __shared__ unsigned short tr1a[NSTATES];
  __shared__ unsigned       flml[NSTATES];  // fl[15:0] (0xFFFF=-1), ml[31:16]
  __shared__ unsigned short rla[NSTATES];   // last end pos, 0xFFFF = -1

  const int row = blockIdx.x;
  const int b = row / C;
  const int c = row - b * C;
  const int lane = threadIdx.x;

  for (int s = lane; s < NSTATES; s += 64) {
    tr0a[s] = 0xFFFFu; tr1a[s] = 0xFFFFu;
    flml[s] = 0x0000FFFFu; rla[s] = 0xFFFFu;
  }

  const size_t rowbase = (size_t)b * (size_t)T * (size_t)C + (size_t)c;
  const float* qr = q + rowbase;
  const float* kr = k + rowbase;
  unsigned* outr = outpos + rowbase;

  // Pre-binarize: lane L holds bits t = 32L..32L+31 of q and k.
  unsigned qw = 0u, kw = 0u;
  {
    const int t0 = lane * 32;
#pragma unroll 8
    for (int jj = 0; jj < 32; ++jj) {
      const int t = t0 + jj;
      if (qr[(size_t)t * C] > 0.0f) qw |= (1u << jj);
      if (kr[(size_t)t * C] > 0.0f) kw |= (1u << jj);
    }
  }
  __syncthreads();

  int cid = 0;                  // my chain slot's state id (slot = lane)
  bool cval = (lane == 0);      // slot validity (valid slots contiguous)
  bool trunc = false;

  int g = 0;    // last state (uniform; used by fallback)
  int mlg = 0;  // ml[g]
  int u = 1;    // next free state id
  int w = 0;    // query-match state
  int h = 0;    // query-match length

  // ---- prologue prefetch for i = 0 ----
  int qs = (int)(__builtin_amdgcn_readlane((int)qw, 0) & 1);
  int ks = (int)(__builtin_amdgcn_readlane((int)kw, 0) & 1);
  unsigned short* tq = qs ? tr1a : tr0a;
  unsigned short* tk = ks ? tr1a : tr0a;
  int      pf_img = (int)(short)tk[cid];
  unsigned pf_fm  = flml[cid];
  int      pf_t1  = (int)(short)tq[w];
  unsigned pf_fm1 = flml[w];

  for (int i = 0; i < T; ++i) {
    const bool hot = !trunc;
    const int img  = pf_img;            // tk[cid], pre-key value (prefetched)
    const int myml = (int)(pf_fm >> 16);

    const int j = u++;
    const int mlj = mlg + 1;

    // persists early -> deferred
    int d = -1, bb = -1, flj = 0, ndd = 0, newlen = 2, pushed = 0;
    unsigned fmd = 0;
    bool prefl = false, inrun = false;

    if (hot) {
      // ---------- EARLY KEY: everything not visible to the query ----------
      const u64m brkmask = __ballot(cval && img != -1);
      const bool nobrk = (brkmask == 0);
      const int t2 = nobrk ? 64 : (int)__builtin_ctzll(brkmask);
      const int t2c = (t2 > 63) ? 63 : t2;
      d = __builtin_amdgcn_readlane(img, t2c);   // uniform idx -> no DS hop
      const int mlp = __builtin_amdgcn_readlane(myml, t2c);
      const int dld = (d < 0) ? 0 : d;
      prefl = cval && (lane < t2);

      // one LDS hop: everything addressed by d (flml untouched by prefix
      // stores; tr[d] patched below if d itself is a prefix-chain node)
      fmd = flml[dld];
      int dtr0 = (int)(short)tr0a[dld];
      int dtr1 = (int)(short)tr1a[dld];
      // prev-lane img for run-start detection (addr ready now)
      int lm1 = lane - 1; if (lm1 < 0) lm1 = 0;
      const int previmg = __builtin_amdgcn_ds_bpermute(lm1 << 2, img);

      if (!nobrk) {
        const int mld = (int)(fmd >> 16);
        if (mlp + 1 == mld) {
          flj = d;
        } else {
          bb = u++;  // clone of d with length mlp+1
          // register patch of the deferred prefix stores' effect on tk[d]
          const u64m pb = __ballot(prefl && cid == d);
          if (pb != 0ull) { if (ks) dtr1 = j; else dtr0 = j; }
          if (lane == 0) {
            // bb is unreachable until the deferred link stores land ->
            // these stores are safe before the query walk
            tr0a[bb] = (unsigned short)dtr0;
            tr1a[bb] = (unsigned short)dtr1;
            // rl[bb] copy elided: bb is slot 1 of the new chain -> stamped i
            flml[bb] = (fmd & 0xFFFFu) | ((unsigned)(mlp + 1) << 16);
          }
          flj = bb;
        }
      }
      if (lane == 0)  // j likewise unreachable during the query
        flml[j] = (unsigned)(flj & 0xFFFF) | ((unsigned)mlj << 16);

      // redirect run (clone only): contiguous img==d from t2
      if (bb >= 0) {
        const u64m eq = __ballot(cval && img == d) >> t2;
        const int runlen = (eq == ~0ull) ? 64 : (int)__builtin_ctzll(~eq);
        inrun = cval && lane >= t2 && lane < t2 + runlen;
      }
      // run-start mask from PRE-redirect img: identical post-redirect, since
      // the redirect replaces a maximal run of d with an equal run of fresh bb
      const bool rs = cval && lane >= t2 && (lane == t2 || img != previmg);
      const u64m rsmask = __ballot(rs);
      ndd = (int)__builtin_popcountll(rsmask);
      newlen = ndd + 2;  // [j] + ndd images + [root]
      const unsigned below =
          __builtin_amdgcn_mbcnt_hi((unsigned)(rsmask >> 32),
              __builtin_amdgcn_mbcnt_lo((unsigned)rsmask, 0u));
      // run-start #q pushes its image to slot q+1; others push to trash
      // slot 0 (only lane 0 reads it, and lane 0 overrides with j).
      // slot 1 is overridden with flj, absorbing the redirect patch.
      const int dst = rs ? ((int)below + 1) : 0;
      pushed = __builtin_amdgcn_ds_permute(dst << 2, img);
    }

    // ============ QUERY (wave-uniform; sees pre-key automaton) ============
    int p = w, x = h;
    {
      int tv = pf_t1; unsigned fm = pf_fm1;  // prefetched tq[w], flml[w]
      for (;;) {
        if (p == -1) { p = 0; x = 0; break; }
        if (tv != -1) { p = tv; x = x + 1; break; }
        const int mp = (int)(fm >> 16);
        if (x > mp) x = mp;
        p = (int)(short)(fm & 0xFFFFu);
        if (p == -1) { p = 0; x = 0; break; }
        tv = (int)(short)tq[p]; fm = flml[p];
      }
    }

    int vst = p;
    unsigned fmv = flml[vst];
    for (;;) {
      const int fv = (int)(short)(fmv & 0xFFFFu);
      if (fv == -1) break;
      const unsigned fmf = flml[fv];
      if ((int)(fmf >> 16) < x) break;
      vst = fv; fmv = fmf;
    }
    int rv = -1;
    for (;;) {
      if (vst == -1) { rv = -1; break; }
      const unsigned fm2 = flml[vst];
      const int r2 = (int)(short)rla[vst];
      if ((int)(fm2 >> 16) > 0 && r2 >= 0) { rv = r2; break; }
      vst = (int)(short)(fm2 & 0xFFFFu);
    }
    w = p; h = x;

    if (hot) {
      // -------- DEFERRED KEY: stores the query must not observe --------
      if (prefl) tk[cid] = (unsigned short)j;
      if (inrun) tk[cid] = (unsigned short)bb;
      if (bb >= 0 && lane == 0)
        flml[d] = (fmd & 0xFFFF0000u) | (unsigned)bb;
      if (lane == 0) outr[(size_t)i * C] = (unsigned)(rv + 1);

      // new chain: [j, flj, run-start images #1.., root]
      int nv = 0;  // default root/padding (safe gather next step)
      if (lane == 0) nv = j;
      else if (lane == 1) nv = flj;
      else if (lane - 1 < ndd) nv = pushed;
      const bool nval = (lane < newlen);
      if (nval) rla[nv] = (unsigned short)i;   // after query's rla reads

      const bool overflow = (newlen > 64);
      if (overflow) {  // cold: stamp the unstored tail serially
        const int nv63 = __builtin_amdgcn_readlane(nv, 63);
        if (lane == 0) {
          int vp = (int)(short)(flml[nv63] & 0xFFFFu);
          while (vp != -1) {
            rla[vp] = (unsigned short)i;
            vp = (int)(short)(flml[vp] & 0xFFFFu);
          }
        }
      }
      cid = nv; cval = nval; trunc = overflow;
    } else {
      // ======= COLD fallback: reference-exact serial step (R10-verified) ====
      int pcur = g, d2 = -1, idbrk = -1;
      for (;;) {
        if (pcur == -1) break;
        const int tv = (int)(short)tk[pcur];
        const unsigned fm = flml[pcur];
        if (tv != -1) { d2 = tv; idbrk = pcur; break; }
        if (lane == 0) tk[pcur] = (unsigned short)j;
        pcur = (int)(short)(fm & 0xFFFFu);
      }
      int fl2 = 0;
      if (d2 != -1) {
        const int mlp = (int)(flml[idbrk] >> 16);
        const unsigned fmd2 = flml[d2];
        const int mld = (int)(fmd2 >> 16);
        if (mlp + 1 == mld) {
          fl2 = d2;
        } else {
          const int bbc = u++;
          const int dtr0 = (int)(short)tr0a[d2];
          const int dtr1 = (int)(short)tr1a[d2];
          const int drl  = (int)(short)rla[d2];
          if (lane == 0) {
            tr0a[bbc] = (unsigned short)dtr0;
            tr1a[bbc] = (unsigned short)dtr1;
            rla[bbc]  = (unsigned short)drl;
            flml[bbc] = (fmd2 & 0xFFFFu) | ((unsigned)(mlp + 1) << 16);
            flml[d2]  = (fmd2 & 0xFFFF0000u) | (unsigned)bbc;
          }
          fl2 = bbc;
          int p3 = idbrk;
          for (;;) {
            if (p3 == -1) break;
            const int tv3 = (int)(short)tk[p3];
            const unsigned fm3 = flml[p3];
            if (tv3 != d2) break;
            if (lane == 0) tk[p3] = (unsigned short)bbc;
            p3 = (int)(short)(fm3 & 0xFFFFu);
          }
        }
      }
      if (lane == 0) {
        flml[j] = (unsigned)(fl2 & 0xFFFF) | ((unsigned)mlj << 16);
        outr[(size_t)i * C] = (unsigned)(rv + 1);
      }
      // full propagation walk; rebuild lane chain while stamping
      int vp = j, ncs = 0;
      bool tr2 = false;
      for (;;) {
        if (vp == -1) break;
        if (ncs < 64) { if (lane == ncs) cid = vp; ++ncs; }
        else tr2 = true;
        if (lane == 0) rla[vp] = (unsigned short)i;
        vp = (int)(short)(flml[vp] & 0xFFFFu);
      }
      cval = (lane < ncs);
      trunc = tr2;
    }
    g = j; mlg = mlj;

    // ---- tail prefetch for i+1 (same-wave DS ops complete in order, so
    // these loads see every store of this step; the early stores of step
    // i+1 touch only fresh indices j'/bb' != cid, w) ----
    if (i + 1 < T) {
      const int in = i + 1;
      const unsigned qwn = (unsigned)__builtin_amdgcn_readlane((int)qw, in >> 5);
      const unsigned kwn = (unsigned)__builtin_amdgcn_readlane((int)kw, in >> 5);
      qs = (int)((qwn >> (in & 31)) & 1u);
      ks = (int)((kwn >> (in & 31)) & 1u);
      tq = qs ? tr1a : tr0a;
      tk = ks ? tr1a : tr0a;
      pf_img = (int)(short)tk[cid];
      pf_fm  = flml[cid];
      pf_t1  = (int)(short)tq[w];
      pf_fm1 = flml[w];
    }
  }
}

// Fully parallel epilogue: vidx (u32, = r+1, 0 = no match) -> sign*e.
__global__ __launch_bounds__(256)
void samx_epilogue(const float* __restrict__ v,
                   const float* __restrict__ e,
                   unsigned* __restrict__ out,
                   int T, int C, int total) {
  const int idx = blockIdx.x * 256 + threadIdx.x;
  if (idx >= total) return;
  const unsigned vidx = out[idx];
  const int c = idx % C;
  const int bi = idx / C;
  const int b = bi / T;
  const float ev = e[c];
  float val = -ev;  // y=0
  if (vidx != 0u) {
    if (v[((size_t)b * (size_t)T + (size_t)vidx) * (size_t)C + (size_t)c] > 0.0f)
      val = ev;
  }
  out[idx] = __float_as_uint(val);
}

extern "C" void kernel_launch(void* const* d_in, const int* in_sizes, int n_in,
                              void* d_out, int out_size, void* d_ws, size_t ws_size,
                              hipStream_t stream) {
  const float* q = (const float*)d_in[0];
  const float* k = (const float*)d_in[1];
  const float* v = (const float*)d_in[2];
  const float* e = (const float*)d_in[3];

  const int C = in_sizes[3];
  const int T = TLEN;
  const int B = in_sizes[0] / (T * C);
  const int total = out_size;

  samx_main<<<dim3(B * C), dim3(64), 0, stream>>>(q, k, (unsigned*)d_out, T, C);
  samx_epilogue<<<dim3((total + 255) / 256), dim3(256), 0, stream>>>(
      v, e, (unsigned*)d_out, T, C, total);
}